// Round 12
// baseline (971.943 us; speedup 1.0000x reference)
//
#include <hip/hip_runtime.h>

// PolicyNetGARCH: B=1024 S=512 OBS=5 NINS=2 H=32 NBLK=4
// Round 12: MFMA datapath (verified in R11: C/D layout == next step's
// B-fragment layout, so h-feedback/xn are in-register cvt_pkrtz packs),
// restructured from 4 waves/WG to 2 waves/WG x 2 blocks/wave:
//   wave 0 = input proj + blocks 0,1 ; wave 1 = blocks 2,3 + head.
// Block->block inside a wave = register residual (no LDS); one cross-wave
// LDS handoff, parity-double-buffered; barrier width 2, skew 1.
// Weights are MFMA A/C operands -> AGPR-native on gfx950 unified file
// (no v_accvgpr copies, unlike R5's v_dot2 attempt).
// Gates G = rinv*(W_ih @ (rw.*xt)) + (W_hh @ h + bias) via
// v_mfma_f32_16x16x32_f16, 8 M-tiles x 2 per block; bias rides as the C
// operand of the h-MFMA; weights prescaled by log2e (2*log2e for g rows,
// M-tiles 4,5) so activations are raw v_exp_f32.
// RMS / head reduces use __shfl_xor - both off the recurrent critical path
// (rinv consumed after x-MFMA latency; head feeds only the global store).

constexpr int B_ = 1024, S_ = 512, OBS_ = 5, NINS_ = 2, H_ = 32, NBLK_ = 4;
constexpr float EPS_ = 1e-6f;
constexpr float LOG2E_ = 1.4426950408889634f;

typedef __fp16 h2 __attribute__((ext_vector_type(2)));
typedef __fp16 h8 __attribute__((ext_vector_type(8)));
typedef float  f4 __attribute__((ext_vector_type(4)));
typedef int    i4 __attribute__((ext_vector_type(4)));

__device__ __forceinline__ float rcp_(float x) { return __builtin_amdgcn_rcpf(x); }
__device__ __forceinline__ float rsq_(float x) { return __builtin_amdgcn_rsqf(x); }
__device__ __forceinline__ float ex2_(float x) { return __builtin_amdgcn_exp2f(x); }
__device__ __forceinline__ h2 pk_(float a, float b) {
  return __builtin_amdgcn_cvt_pkrtz(a, b);
}
// pack 8 f32 (k-chunk0 = lo, k-chunk1 = hi) into an f16x8 MFMA fragment
__device__ __forceinline__ h8 pk8_(f4 lo, f4 hi) {
  i4 q;
  q[0] = __builtin_bit_cast(int, pk_(lo[0], lo[1]));
  q[1] = __builtin_bit_cast(int, pk_(lo[2], lo[3]));
  q[2] = __builtin_bit_cast(int, pk_(hi[0], hi[1]));
  q[3] = __builtin_bit_cast(int, pk_(hi[2], hi[3]));
  return __builtin_bit_cast(h8, q);
}
__device__ __forceinline__ f4 mfma_(h8 a, h8 b, f4 c) {
  return __builtin_amdgcn_mfma_f32_16x16x32_f16(a, b, c, 0, 0, 0);
}
// sigmoid, input prescaled by log2e
__device__ __forceinline__ f4 sg4_(f4 a) {
  f4 r;
  r[0] = rcp_(1.f + ex2_(-a[0]));
  r[1] = rcp_(1.f + ex2_(-a[1]));
  r[2] = rcp_(1.f + ex2_(-a[2]));
  r[3] = rcp_(1.f + ex2_(-a[3]));
  return r;
}
// tanh, input prescaled by 2*log2e
__device__ __forceinline__ f4 th4_(f4 a) {
  f4 r;
  r[0] = fmaf(2.f, rcp_(1.f + ex2_(-a[0])), -1.f);
  r[1] = fmaf(2.f, rcp_(1.f + ex2_(-a[1])), -1.f);
  r[2] = fmaf(2.f, rcp_(1.f + ex2_(-a[2])), -1.f);
  r[3] = fmaf(2.f, rcp_(1.f + ex2_(-a[3])), -1.f);
  return r;
}
// tanh of linear-domain c
__device__ __forceinline__ f4 thc4_(f4 c) {
  constexpr float M = 2.f * LOG2E_;
  f4 r;
  r[0] = fmaf(2.f, rcp_(1.f + ex2_(-M * c[0])), -1.f);
  r[1] = fmaf(2.f, rcp_(1.f + ex2_(-M * c[1])), -1.f);
  r[2] = fmaf(2.f, rcp_(1.f + ex2_(-M * c[2])), -1.f);
  r[3] = fmaf(2.f, rcp_(1.f + ex2_(-M * c[3])), -1.f);
  return r;
}
__device__ __forceinline__ float dot44_(f4 a, f4 x, f4 b2, f4 y) {
  float s = a[0] * x[0];
  s = fmaf(a[1], x[1], s); s = fmaf(a[2], x[2], s); s = fmaf(a[3], x[3], s);
  s = fmaf(b2[0], y[0], s); s = fmaf(b2[1], y[1], s);
  s = fmaf(b2[2], y[2], s); s = fmaf(b2[3], y[3], s);
  return s;
}

// Load one block's A-fragments/biases (exp2-prescaled) into named arrays.
#define LOAD_BLK(KG, WX, WH, BS, RW0, RW1) do {                            \
    const size_t _wb = (size_t)(KG) * 128 * 32;                            \
    _Pragma("unroll")                                                      \
    for (int mi = 0; mi < 8; ++mi) {                                       \
      const float scl = (mi == 4 || mi == 5) ? 2.f * LOG2E_ : LOG2E_;      \
      const int row = 16 * mi + b;                                         \
      const float* px = W_ih + _wb + (size_t)row * 32;                     \
      f4 x0 = *(const f4*)(px + 4 * g);                                    \
      f4 x1 = *(const f4*)(px + 16 + 4 * g);                               \
      WX[mi] = pk8_(x0 * scl, x1 * scl);                                   \
      const float* ph = W_hh + _wb + (size_t)row * 32;                     \
      f4 h0v = *(const f4*)(ph + 4 * g);                                   \
      f4 h1v = *(const f4*)(ph + 16 + 4 * g);                              \
      WH[mi] = pk8_(h0v * scl, h1v * scl);                                 \
      f4 bv;                                                               \
      _Pragma("unroll")                                                    \
      for (int r = 0; r < 4; ++r) {                                        \
        const int gr = (KG) * 128 + 16 * mi + 4 * g + r;                   \
        bv[r] = (b_ih[gr] + b_hh[gr]) * scl;                               \
      }                                                                    \
      BS[mi] = bv;                                                         \
    }                                                                      \
    _Pragma("unroll")                                                      \
    for (int r = 0; r < 4; ++r) {                                          \
      RW0[r] = rms_w[(KG) * 32 + 4 * g + r];                               \
      RW1[r] = rms_w[(KG) * 32 + 16 + 4 * g + r];                          \
    }                                                                      \
  } while (0)

// One LSTM block step (RMS + 16 MFMA + activations); updates C*, HV*, XT*.
#define BLK_STEP(WX, WH, BS, RW0, RW1, C0, C1, HV0, HV1, XT0, XT1) do {    \
    float _ss = dot44_((XT0), (XT0), (XT1), (XT1));                        \
    _ss += __shfl_xor(_ss, 16);                                            \
    _ss += __shfl_xor(_ss, 32);                                            \
    const float _rinv = rsq_(_ss * (1.0f / 32.0f) + EPS_);                 \
    const h8 _bx = pk8_((XT0) * (RW0), (XT1) * (RW1));                     \
    const h8 _bh = pk8_((HV0), (HV1));                                     \
    const f4 _z = {};                                                      \
    f4 _ax, _ah, _gi0, _gi1, _gf0, _gf1, _gg0, _gg1, _go0, _go1;           \
    _ax = mfma_(WX[0], _bx, _z); _ah = mfma_(WH[0], _bh, BS[0]); _gi0 = _ax * _rinv + _ah; \
    _ax = mfma_(WX[1], _bx, _z); _ah = mfma_(WH[1], _bh, BS[1]); _gi1 = _ax * _rinv + _ah; \
    _ax = mfma_(WX[2], _bx, _z); _ah = mfma_(WH[2], _bh, BS[2]); _gf0 = _ax * _rinv + _ah; \
    _ax = mfma_(WX[3], _bx, _z); _ah = mfma_(WH[3], _bh, BS[3]); _gf1 = _ax * _rinv + _ah; \
    _ax = mfma_(WX[4], _bx, _z); _ah = mfma_(WH[4], _bh, BS[4]); _gg0 = _ax * _rinv + _ah; \
    _ax = mfma_(WX[5], _bx, _z); _ah = mfma_(WH[5], _bh, BS[5]); _gg1 = _ax * _rinv + _ah; \
    _ax = mfma_(WX[6], _bx, _z); _ah = mfma_(WH[6], _bh, BS[6]); _go0 = _ax * _rinv + _ah; \
    _ax = mfma_(WX[7], _bx, _z); _ah = mfma_(WH[7], _bh, BS[7]); _go1 = _ax * _rinv + _ah; \
    const f4 _si0 = sg4_(_gi0), _si1 = sg4_(_gi1);                         \
    const f4 _sf0 = sg4_(_gf0), _sf1 = sg4_(_gf1);                         \
    const f4 _tg0 = th4_(_gg0), _tg1 = th4_(_gg1);                         \
    const f4 _so0 = sg4_(_go0), _so1 = sg4_(_go1);                         \
    (C0) = _sf0 * (C0) + _si0 * _tg0;                                      \
    (C1) = _sf1 * (C1) + _si1 * _tg1;                                      \
    (HV0) = _so0 * thc4_(C0);                                              \
    (HV1) = _so1 * thc4_(C1);                                              \
    (XT0) += (HV0);                                                        \
    (XT1) += (HV1);                                                        \
  } while (0)

__global__ __launch_bounds__(128, 1) void garch_mfma2_kernel(
    const float* __restrict__ obs, const float* __restrict__ prev,
    const float* __restrict__ W_in, const float* __restrict__ b_in,
    const float* __restrict__ rms_w,
    const float* __restrict__ W_ih, const float* __restrict__ W_hh,
    const float* __restrict__ b_ih, const float* __restrict__ b_hh,
    const float* __restrict__ head_w, const float* __restrict__ head_b,
    float* __restrict__ out) {
  const int tid  = threadIdx.x;
  const int w    = tid >> 6;        // wave role: 0 = proj+blk0,1 ; 1 = blk2,3+head
  const int lane = tid & 63;
  const int g    = lane >> 4;       // k-chunk / row group
  const int b    = lane & 15;       // batch column within tile
  const int bg   = blockIdx.x * 16 + b;

  // cross-wave xt handoff (parity dbuf), C-layout addressed
  __shared__ __align__(16) float xslot[2][16][36];

  // ---- weights for this wave's two blocks (A = 2w, B = 2w+1) ----
  h8 wxA[8], whA[8], wxB[8], whB[8];
  f4 bsA[8], bsB[8];
  f4 rwA0, rwA1, rwB0, rwB1;
  LOAD_BLK(2 * w,     wxA, whA, bsA, rwA0, rwA1);
  LOAD_BLK(2 * w + 1, wxB, whB, bsB, rwB0, rwB1);

  // ---- role-specific constants ----
  h8 winA0 = {}, winA1 = {};
  f4 bin0v = {}, bin1v = {};
  const float* obs_b = nullptr; const float* prev_b = nullptr;
  float cur0 = 0.f, cur1 = 0.f, cur2 = 0.f, cur3 = 0.f;
  float nx0 = 0.f, nx1 = 0.f, nx2 = 0.f, nx3 = 0.f;
  f4 hw00 = {}, hw01 = {}, hw10 = {}, hw11 = {};
  float hb0 = 0.f, hb1 = 0.f;
  if (w == 0) {
    f4 lo0, lo1; const f4 z = {};
#pragma unroll
    for (int r = 0; r < 4; ++r) {
      const int kk = 4 * g + r;
      lo0[r] = (kk < 7) ? W_in[(size_t)b * 7 + kk] : 0.f;
      lo1[r] = (kk < 7) ? W_in[(size_t)(16 + b) * 7 + kk] : 0.f;
    }
    winA0 = pk8_(lo0, z);
    winA1 = pk8_(lo1, z);
#pragma unroll
    for (int r = 0; r < 4; ++r) {
      bin0v[r] = b_in[4 * g + r];
      bin1v[r] = b_in[16 + 4 * g + r];
    }
    obs_b  = obs  + (size_t)bg * S_ * OBS_;
    prev_b = prev + (size_t)bg * S_ * NINS_;
    if (g == 0)      { cur0 = obs_b[0]; cur1 = obs_b[1]; cur2 = obs_b[2]; cur3 = obs_b[3]; }
    else if (g == 1) { cur0 = obs_b[4]; cur1 = prev_b[0]; cur2 = prev_b[1]; cur3 = 0.f; }
  } else {
#pragma unroll
    for (int r = 0; r < 4; ++r) {
      hw00[r] = head_w[4 * g + r]      * LOG2E_;
      hw01[r] = head_w[16 + 4 * g + r] * LOG2E_;
      hw10[r] = head_w[32 + 4 * g + r] * LOG2E_;
      hw11[r] = head_w[48 + 4 * g + r] * LOG2E_;
    }
    hb0 = head_b[0] * LOG2E_;
    hb1 = head_b[1] * LOG2E_;
  }

  // state for the wave's two blocks
  f4 cA0 = {}, cA1 = {}, hA0 = {}, hA1 = {};
  f4 cB0 = {}, cB1 = {}, hB0 = {}, hB1 = {};

  float* out_y  = out;                                // [2][B][S]
  float* out_hT = out + (size_t)NINS_ * B_ * S_;      // [4][B][H]
  float* out_cT = out_hT + (size_t)NBLK_ * B_ * H_;   // [4][B][H]

  for (int tau = 0; tau <= S_; ++tau) {
    __syncthreads();                  // every thread, every tick
    const int t = tau - w;            // wave-uniform window
    if (t < 0 || t >= S_) continue;
    const int wp = tau & 1, rp = (tau + 1) & 1;

    // ---- 1. xt tiles ----
    f4 xt0, xt1;
    if (w == 0) {
      if (t + 1 < S_) {               // prefetch next tick's inputs
        const float* o2 = obs_b + (size_t)(t + 1) * OBS_;
        if (g == 0)      { nx0 = o2[0]; nx1 = o2[1]; nx2 = o2[2]; nx3 = o2[3]; }
        else if (g == 1) { nx0 = o2[4]; nx1 = prev_b[2 * (t + 1)]; nx2 = prev_b[2 * (t + 1) + 1]; nx3 = 0.f; }
      }
      const f4 lo = { cur0, cur1, cur2, cur3 };  // g>=2 lanes: zeros
      const f4 z = {};
      const h8 binp = pk8_(lo, z);
      xt0 = mfma_(winA0, binp, bin0v);
      xt1 = mfma_(winA1, binp, bin1v);
    } else {
      xt0 = *(const f4*)&xslot[rp][b][4 * g];
      xt1 = *(const f4*)&xslot[rp][b][16 + 4 * g];
    }

    // ---- 2. two LSTM blocks, register residual between them ----
    BLK_STEP(wxA, whA, bsA, rwA0, rwA1, cA0, cA1, hA0, hA1, xt0, xt1);
    BLK_STEP(wxB, whB, bsB, rwB0, rwB1, cB0, cB1, hB0, hB1, xt0, xt1);

    // ---- 3. handoff or head ----
    if (w == 0) {
      *(f4*)&xslot[wp][b][4 * g]      = xt0;
      *(f4*)&xslot[wp][b][16 + 4 * g] = xt1;
      if (t == S_ - 1) {
        float* hp0 = out_hT + ((size_t)0 * B_ + bg) * H_;
        float* hp1 = out_hT + ((size_t)1 * B_ + bg) * H_;
        float* cp0 = out_cT + ((size_t)0 * B_ + bg) * H_;
        float* cp1 = out_cT + ((size_t)1 * B_ + bg) * H_;
#pragma unroll
        for (int r = 0; r < 4; ++r) {
          hp0[4 * g + r] = hA0[r]; hp0[16 + 4 * g + r] = hA1[r];
          hp1[4 * g + r] = hB0[r]; hp1[16 + 4 * g + r] = hB1[r];
          cp0[4 * g + r] = cA0[r]; cp0[16 + 4 * g + r] = cA1[r];
          cp1[4 * g + r] = cB0[r]; cp1[16 + 4 * g + r] = cB1[r];
        }
      }
      cur0 = nx0; cur1 = nx1; cur2 = nx2; cur3 = nx3;
    } else {
      float p0 = dot44_(hw00, xt0, hw01, xt1);
      float p1 = dot44_(hw10, xt0, hw11, xt1);
      p0 += __shfl_xor(p0, 16); p0 += __shfl_xor(p0, 32);
      p1 += __shfl_xor(p1, 16); p1 += __shfl_xor(p1, 32);
      p0 += hb0; p1 += hb1;
      if (lane < 16) {
        const float v0 = copysignf(fminf(ex2_(fabsf(p0)) - 1.f, 5.f),  p0);
        const float v1 = copysignf(fminf(ex2_(fabsf(p1)) - 1.f, 10.f), p1);
        out_y[(size_t)bg * S_ + t]                    = v0;
        out_y[(size_t)B_ * S_ + (size_t)bg * S_ + t]  = v1;
      }
      if (t == S_ - 1) {
        float* hp2 = out_hT + ((size_t)2 * B_ + bg) * H_;
        float* hp3 = out_hT + ((size_t)3 * B_ + bg) * H_;
        float* cp2 = out_cT + ((size_t)2 * B_ + bg) * H_;
        float* cp3 = out_cT + ((size_t)3 * B_ + bg) * H_;
#pragma unroll
        for (int r = 0; r < 4; ++r) {
          hp2[4 * g + r] = hA0[r]; hp2[16 + 4 * g + r] = hA1[r];
          hp3[4 * g + r] = hB0[r]; hp3[16 + 4 * g + r] = hB1[r];
          cp2[4 * g + r] = cA0[r]; cp2[16 + 4 * g + r] = cA1[r];
          cp3[4 * g + r] = cB0[r]; cp3[16 + 4 * g + r] = cB1[r];
        }
      }
    }
  }
}

extern "C" void kernel_launch(void* const* d_in, const int* in_sizes, int n_in,
                              void* d_out, int out_size, void* d_ws, size_t ws_size,
                              hipStream_t stream) {
  (void)in_sizes; (void)n_in; (void)d_ws; (void)ws_size; (void)out_size;
  garch_mfma2_kernel<<<dim3(B_ / 16), dim3(128), 0, stream>>>(
      (const float*)d_in[0],  // obs_sequence [B,S,OBS]
      (const float*)d_in[1],  // prev_actions [B,S,NINS]
      (const float*)d_in[2],  // W_in [H, OBS+NINS]
      (const float*)d_in[3],  // b_in [H]
      (const float*)d_in[4],  // rms_w [NBLK,H]
      (const float*)d_in[5],  // W_ih [NBLK,4H,H]
      (const float*)d_in[6],  // W_hh [NBLK,4H,H]
      (const float*)d_in[7],  // b_ih [NBLK,4H]
      (const float*)d_in[8],  // b_hh [NBLK,4H]
      (const float*)d_in[9],  // head_w [NINS,H]
      (const float*)d_in[10], // head_b [NINS]
      (float*)d_out);
}

// Round 13
// 540.866 us; speedup vs baseline: 1.7970x; 1.7970x over previous
//
#include <hip/hip_runtime.h>

// PolicyNetGARCH: B=1024 S=512 OBS=5 NINS=2 H=32 NBLK=4
// Round 13: R11's verified MFMA structure (4 waves/WG, wave k = block k,
// 16 batch cols/WG, skewed pipeline, parity-dbuf LDS xt handoff) plus:
//  (1) super-tick = 2 timesteps per barrier (halves barriers/slot reads;
//      step B's x-side is independent of step A's chain -> in-wave ILP),
//  (2) RMS/head reduces via v_permlane16_swap/v_permlane32_swap (VALU)
//      instead of __shfl_xor (LDS pipe, ~120cy each).
// Datapath (verified R11/R12): C/D layout == next step's B-fragment layout,
// so h-feedback/xn are in-register cvt_pkrtz packs. Gates
// G = rinv*(W_ih @ (rw.*xt)) + (W_hh @ h + bias) via mfma_f32_16x16x32_f16,
// bias as the h-MFMA's C operand; weights prescaled by log2e (2*log2e for
// g-rows, M-tiles 4,5) so activations are raw v_exp_f32.

constexpr int B_ = 1024, S_ = 512, OBS_ = 5, NINS_ = 2, H_ = 32, NBLK_ = 4;
constexpr int TT_ = S_ / 2;    // super-ticks
constexpr float EPS_ = 1e-6f;
constexpr float LOG2E_ = 1.4426950408889634f;

typedef __fp16 h2 __attribute__((ext_vector_type(2)));
typedef __fp16 h8 __attribute__((ext_vector_type(8)));
typedef float  f4 __attribute__((ext_vector_type(4)));
typedef int    i4 __attribute__((ext_vector_type(4)));

__device__ __forceinline__ float rcp_(float x) { return __builtin_amdgcn_rcpf(x); }
__device__ __forceinline__ float rsq_(float x) { return __builtin_amdgcn_rsqf(x); }
__device__ __forceinline__ float ex2_(float x) { return __builtin_amdgcn_exp2f(x); }
__device__ __forceinline__ h2 pk_(float a, float b) {
  return __builtin_amdgcn_cvt_pkrtz(a, b);
}
__device__ __forceinline__ h8 pk8_(f4 lo, f4 hi) {
  i4 q;
  q[0] = __builtin_bit_cast(int, pk_(lo[0], lo[1]));
  q[1] = __builtin_bit_cast(int, pk_(lo[2], lo[3]));
  q[2] = __builtin_bit_cast(int, pk_(hi[0], hi[1]));
  q[3] = __builtin_bit_cast(int, pk_(hi[2], hi[3]));
  return __builtin_bit_cast(h8, q);
}
__device__ __forceinline__ f4 mfma_(h8 a, h8 b, f4 c) {
  return __builtin_amdgcn_mfma_f32_16x16x32_f16(a, b, c, 0, 0, 0);
}
__device__ __forceinline__ f4 sg4_(f4 a) {          // sigmoid, log2e-prescaled
  f4 r;
  r[0] = rcp_(1.f + ex2_(-a[0]));
  r[1] = rcp_(1.f + ex2_(-a[1]));
  r[2] = rcp_(1.f + ex2_(-a[2]));
  r[3] = rcp_(1.f + ex2_(-a[3]));
  return r;
}
__device__ __forceinline__ f4 th4_(f4 a) {          // tanh, 2*log2e-prescaled
  f4 r;
  r[0] = fmaf(2.f, rcp_(1.f + ex2_(-a[0])), -1.f);
  r[1] = fmaf(2.f, rcp_(1.f + ex2_(-a[1])), -1.f);
  r[2] = fmaf(2.f, rcp_(1.f + ex2_(-a[2])), -1.f);
  r[3] = fmaf(2.f, rcp_(1.f + ex2_(-a[3])), -1.f);
  return r;
}
__device__ __forceinline__ f4 thc4_(f4 c) {         // tanh of linear c
  constexpr float M = 2.f * LOG2E_;
  f4 r;
  r[0] = fmaf(2.f, rcp_(1.f + ex2_(-M * c[0])), -1.f);
  r[1] = fmaf(2.f, rcp_(1.f + ex2_(-M * c[1])), -1.f);
  r[2] = fmaf(2.f, rcp_(1.f + ex2_(-M * c[2])), -1.f);
  r[3] = fmaf(2.f, rcp_(1.f + ex2_(-M * c[3])), -1.f);
  return r;
}
__device__ __forceinline__ float dot44_(f4 a, f4 x, f4 b2, f4 y) {
  float s = a[0] * x[0];
  s = fmaf(a[1], x[1], s); s = fmaf(a[2], x[2], s); s = fmaf(a[3], x[3], s);
  s = fmaf(b2[0], y[0], s); s = fmaf(b2[1], y[1], s);
  s = fmaf(b2[2], y[2], s); s = fmaf(b2[3], y[3], s);
  return s;
}
// partner across lane^16 (VALU permlane; re = even 16-row)
__device__ __forceinline__ float psw16_(float v, bool re) {
#if __has_builtin(__builtin_amdgcn_permlane16_swap)
  auto r = __builtin_amdgcn_permlane16_swap(
      __builtin_bit_cast(int, v), __builtin_bit_cast(int, v), false, false);
  return __builtin_bit_cast(float, re ? (int)r[1] : (int)r[0]);
#else
  return __shfl_xor(v, 16);
#endif
}
// partner across lane^32 (VALU permlane; lo = lane<32)
__device__ __forceinline__ float psw32_(float v, bool lo) {
#if __has_builtin(__builtin_amdgcn_permlane32_swap)
  auto r = __builtin_amdgcn_permlane32_swap(
      __builtin_bit_cast(int, v), __builtin_bit_cast(int, v), false, false);
  return __builtin_bit_cast(float, lo ? (int)r[1] : (int)r[0]);
#else
  return __shfl_xor(v, 32);
#endif
}

// One LSTM block step (uses kernel-scope wx/wh/biasv/rw0v/rw1v, state
// c0/c1/hv0/hv1, bools re_/lo_). Updates state and XT in place.
#define BLK_STEP(XT0, XT1) do {                                            \
    float _ss = dot44_((XT0), (XT0), (XT1), (XT1));                        \
    _ss += psw16_(_ss, re_);                                               \
    _ss += psw32_(_ss, lo_);                                               \
    const float _rinv = rsq_(_ss * (1.0f / 32.0f) + EPS_);                 \
    const h8 _bx = pk8_((XT0) * rw0v, (XT1) * rw1v);                       \
    const h8 _bh = pk8_(hv0, hv1);                                         \
    const f4 _z = {};                                                      \
    f4 _ax, _ah, _gi0, _gi1, _gf0, _gf1, _gg0, _gg1, _go0, _go1;           \
    _ax = mfma_(wx[0], _bx, _z); _ah = mfma_(wh[0], _bh, biasv[0]); _gi0 = _ax * _rinv + _ah; \
    _ax = mfma_(wx[1], _bx, _z); _ah = mfma_(wh[1], _bh, biasv[1]); _gi1 = _ax * _rinv + _ah; \
    _ax = mfma_(wx[2], _bx, _z); _ah = mfma_(wh[2], _bh, biasv[2]); _gf0 = _ax * _rinv + _ah; \
    _ax = mfma_(wx[3], _bx, _z); _ah = mfma_(wh[3], _bh, biasv[3]); _gf1 = _ax * _rinv + _ah; \
    _ax = mfma_(wx[4], _bx, _z); _ah = mfma_(wh[4], _bh, biasv[4]); _gg0 = _ax * _rinv + _ah; \
    _ax = mfma_(wx[5], _bx, _z); _ah = mfma_(wh[5], _bh, biasv[5]); _gg1 = _ax * _rinv + _ah; \
    _ax = mfma_(wx[6], _bx, _z); _ah = mfma_(wh[6], _bh, biasv[6]); _go0 = _ax * _rinv + _ah; \
    _ax = mfma_(wx[7], _bx, _z); _ah = mfma_(wh[7], _bh, biasv[7]); _go1 = _ax * _rinv + _ah; \
    const f4 _si0 = sg4_(_gi0), _si1 = sg4_(_gi1);                         \
    const f4 _sf0 = sg4_(_gf0), _sf1 = sg4_(_gf1);                         \
    const f4 _tg0 = th4_(_gg0), _tg1 = th4_(_gg1);                         \
    const f4 _so0 = sg4_(_go0), _so1 = sg4_(_go1);                         \
    c0 = _sf0 * c0 + _si0 * _tg0;                                          \
    c1 = _sf1 * c1 + _si1 * _tg1;                                          \
    hv0 = _so0 * thc4_(c0);                                                \
    hv1 = _so1 * thc4_(c1);                                                \
    (XT0) += hv0;                                                          \
    (XT1) += hv1;                                                          \
  } while (0)

__global__ __launch_bounds__(256, 1) void garch_mfma3_kernel(
    const float* __restrict__ obs, const float* __restrict__ prev,
    const float* __restrict__ W_in, const float* __restrict__ b_in,
    const float* __restrict__ rms_w,
    const float* __restrict__ W_ih, const float* __restrict__ W_hh,
    const float* __restrict__ b_ih, const float* __restrict__ b_hh,
    const float* __restrict__ head_w, const float* __restrict__ head_b,
    float* __restrict__ out) {
  const int tid  = threadIdx.x;
  const int k    = tid >> 6;        // wave role == LSTM block
  const int lane = tid & 63;
  const int g    = lane >> 4;       // k-chunk / row group
  const int b    = lane & 15;       // batch column within tile
  const int bg   = blockIdx.x * 16 + b;
  const bool re_ = ((lane >> 4) & 1) == 0;   // even 16-row
  const bool lo_ = (lane < 32);

  // xt handoff: [stage][parity][step][bcol][32 rows + pad]
  __shared__ __align__(16) float xslot[3][2][2][16][36];

  // ---- A-fragments / biases for this wave's block (exp2-prescaled) ----
  h8 wx[8], wh[8];
  f4 biasv[8];
  {
    const size_t wb = (size_t)k * 128 * 32;
#pragma unroll
    for (int mi = 0; mi < 8; ++mi) {
      const float scl = (mi == 4 || mi == 5) ? 2.f * LOG2E_ : LOG2E_;
      const int row = 16 * mi + b;
      const float* px = W_ih + wb + (size_t)row * 32;
      f4 x0 = *(const f4*)(px + 4 * g);
      f4 x1 = *(const f4*)(px + 16 + 4 * g);
      wx[mi] = pk8_(x0 * scl, x1 * scl);
      const float* ph = W_hh + wb + (size_t)row * 32;
      f4 h0v = *(const f4*)(ph + 4 * g);
      f4 h1v = *(const f4*)(ph + 16 + 4 * g);
      wh[mi] = pk8_(h0v * scl, h1v * scl);
      f4 bv;
#pragma unroll
      for (int r = 0; r < 4; ++r) {
        const int gr = k * 128 + 16 * mi + 4 * g + r;
        bv[r] = (b_ih[gr] + b_hh[gr]) * scl;
      }
      biasv[mi] = bv;
    }
  }
  f4 rw0v, rw1v;
#pragma unroll
  for (int r = 0; r < 4; ++r) {
    rw0v[r] = rms_w[k * 32 + 4 * g + r];
    rw1v[r] = rms_w[k * 32 + 16 + 4 * g + r];
  }

  // ---- role-specific constants ----
  h8 winA0 = {}, winA1 = {};
  f4 bin0v = {}, bin1v = {};
  const float* obs_b = nullptr; const float* prev_b = nullptr;
  float cA0 = 0.f, cA1 = 0.f, cA2 = 0.f, cA3 = 0.f;   // step-A inputs
  float cB0 = 0.f, cB1 = 0.f, cB2 = 0.f, cB3 = 0.f;   // step-B inputs
  float nA0 = 0.f, nA1 = 0.f, nA2 = 0.f, nA3 = 0.f;
  float nB0 = 0.f, nB1 = 0.f, nB2 = 0.f, nB3 = 0.f;
  if (k == 0) {
    f4 lo0, lo1; const f4 z = {};
#pragma unroll
    for (int r = 0; r < 4; ++r) {
      const int kk = 4 * g + r;
      lo0[r] = (kk < 7) ? W_in[(size_t)b * 7 + kk] : 0.f;
      lo1[r] = (kk < 7) ? W_in[(size_t)(16 + b) * 7 + kk] : 0.f;
    }
    winA0 = pk8_(lo0, z);
    winA1 = pk8_(lo1, z);
#pragma unroll
    for (int r = 0; r < 4; ++r) {
      bin0v[r] = b_in[4 * g + r];
      bin1v[r] = b_in[16 + 4 * g + r];
    }
    obs_b  = obs  + (size_t)bg * S_ * OBS_;
    prev_b = prev + (size_t)bg * S_ * NINS_;
    if (g == 0) {
      cA0 = obs_b[0]; cA1 = obs_b[1]; cA2 = obs_b[2]; cA3 = obs_b[3];
      cB0 = obs_b[5]; cB1 = obs_b[6]; cB2 = obs_b[7]; cB3 = obs_b[8];
    } else if (g == 1) {
      cA0 = obs_b[4]; cA1 = prev_b[0]; cA2 = prev_b[1]; cA3 = 0.f;
      cB0 = obs_b[9]; cB1 = prev_b[2]; cB2 = prev_b[3]; cB3 = 0.f;
    }
  }
  f4 hw00 = {}, hw01 = {}, hw10 = {}, hw11 = {};
  float hb0 = 0.f, hb1 = 0.f;
  if (k == 3) {
#pragma unroll
    for (int r = 0; r < 4; ++r) {
      hw00[r] = head_w[4 * g + r]      * LOG2E_;
      hw01[r] = head_w[16 + 4 * g + r] * LOG2E_;
      hw10[r] = head_w[32 + 4 * g + r] * LOG2E_;
      hw11[r] = head_w[48 + 4 * g + r] * LOG2E_;
    }
    hb0 = head_b[0] * LOG2E_;
    hb1 = head_b[1] * LOG2E_;
  }

  // block state
  f4 c0 = {}, c1 = {}, hv0 = {}, hv1 = {};

  float* out_y  = out;                                // [2][B][S]
  float* out_hT = out + (size_t)NINS_ * B_ * S_;      // [4][B][H]
  float* out_cT = out_hT + (size_t)NBLK_ * B_ * H_;   // [4][B][H]

  for (int tau = 0; tau < TT_ + NBLK_ - 1; ++tau) {
    __syncthreads();
    const int tt = tau - k;           // wave-uniform super-tick window
    if (tt < 0 || tt >= TT_) continue;
    const int t0 = 2 * tt;
    const int wp = tau & 1, rp = (tau + 1) & 1;

    // ---- 1. xt tiles for both timesteps ----
    f4 xtA0, xtA1, xtB0, xtB1;
    if (k == 0) {
      if (tt + 1 < TT_) {             // prefetch next super-tick's inputs
        const float* oA = obs_b + (size_t)(t0 + 2) * OBS_;
        const float* oB = obs_b + (size_t)(t0 + 3) * OBS_;
        if (g == 0) {
          nA0 = oA[0]; nA1 = oA[1]; nA2 = oA[2]; nA3 = oA[3];
          nB0 = oB[0]; nB1 = oB[1]; nB2 = oB[2]; nB3 = oB[3];
        } else if (g == 1) {
          nA0 = oA[4]; nA1 = prev_b[2 * (t0 + 2)]; nA2 = prev_b[2 * (t0 + 2) + 1]; nA3 = 0.f;
          nB0 = oB[4]; nB1 = prev_b[2 * (t0 + 3)]; nB2 = prev_b[2 * (t0 + 3) + 1]; nB3 = 0.f;
        }
      }
      const f4 z = {};
      const f4 loA = { cA0, cA1, cA2, cA3 };
      const f4 loB = { cB0, cB1, cB2, cB3 };
      const h8 binA = pk8_(loA, z);
      const h8 binB = pk8_(loB, z);
      xtA0 = mfma_(winA0, binA, bin0v);
      xtA1 = mfma_(winA1, binA, bin1v);
      xtB0 = mfma_(winA0, binB, bin0v);
      xtB1 = mfma_(winA1, binB, bin1v);
    } else {
      xtA0 = *(const f4*)&xslot[k - 1][rp][0][b][4 * g];
      xtA1 = *(const f4*)&xslot[k - 1][rp][0][b][16 + 4 * g];
      xtB0 = *(const f4*)&xslot[k - 1][rp][1][b][4 * g];
      xtB1 = *(const f4*)&xslot[k - 1][rp][1][b][16 + 4 * g];
    }

    // ---- 2. two timesteps of this wave's block ----
    BLK_STEP(xtA0, xtA1);
    BLK_STEP(xtB0, xtB1);

    // ---- 3. handoff or head ----
    if (k < 3) {
      *(f4*)&xslot[k][wp][0][b][4 * g]      = xtA0;
      *(f4*)&xslot[k][wp][0][b][16 + 4 * g] = xtA1;
      *(f4*)&xslot[k][wp][1][b][4 * g]      = xtB0;
      *(f4*)&xslot[k][wp][1][b][16 + 4 * g] = xtB1;
    } else {
      float p0A = dot44_(hw00, xtA0, hw01, xtA1);
      float p1A = dot44_(hw10, xtA0, hw11, xtA1);
      float p0B = dot44_(hw00, xtB0, hw01, xtB1);
      float p1B = dot44_(hw10, xtB0, hw11, xtB1);
      p0A += psw16_(p0A, re_); p0A += psw32_(p0A, lo_);
      p1A += psw16_(p1A, re_); p1A += psw32_(p1A, lo_);
      p0B += psw16_(p0B, re_); p0B += psw32_(p0B, lo_);
      p1B += psw16_(p1B, re_); p1B += psw32_(p1B, lo_);
      p0A += hb0; p1A += hb1; p0B += hb0; p1B += hb1;
      if (lane < 16) {
        const float v0A = copysignf(fminf(ex2_(fabsf(p0A)) - 1.f, 5.f),  p0A);
        const float v0B = copysignf(fminf(ex2_(fabsf(p0B)) - 1.f, 5.f),  p0B);
        const float v1A = copysignf(fminf(ex2_(fabsf(p1A)) - 1.f, 10.f), p1A);
        const float v1B = copysignf(fminf(ex2_(fabsf(p1B)) - 1.f, 10.f), p1B);
        *(float2*)&out_y[(size_t)bg * S_ + t0]                   = make_float2(v0A, v0B);
        *(float2*)&out_y[(size_t)B_ * S_ + (size_t)bg * S_ + t0] = make_float2(v1A, v1B);
      }
    }

    // ---- 4. final states (t = S-1 is step B of the last super-tick) ----
    if (tt == TT_ - 1) {
      float* hp = out_hT + ((size_t)k * B_ + bg) * H_;
      float* cp = out_cT + ((size_t)k * B_ + bg) * H_;
#pragma unroll
      for (int r = 0; r < 4; ++r) {
        hp[4 * g + r]      = hv0[r];
        hp[16 + 4 * g + r] = hv1[r];
        cp[4 * g + r]      = c0[r];
        cp[16 + 4 * g + r] = c1[r];
      }
    }

    if (k == 0) {
      cA0 = nA0; cA1 = nA1; cA2 = nA2; cA3 = nA3;
      cB0 = nB0; cB1 = nB1; cB2 = nB2; cB3 = nB3;
    }
  }
}

extern "C" void kernel_launch(void* const* d_in, const int* in_sizes, int n_in,
                              void* d_out, int out_size, void* d_ws, size_t ws_size,
                              hipStream_t stream) {
  (void)in_sizes; (void)n_in; (void)d_ws; (void)ws_size; (void)out_size;
  garch_mfma3_kernel<<<dim3(B_ / 16), dim3(256), 0, stream>>>(
      (const float*)d_in[0],  // obs_sequence [B,S,OBS]
      (const float*)d_in[1],  // prev_actions [B,S,NINS]
      (const float*)d_in[2],  // W_in [H, OBS+NINS]
      (const float*)d_in[3],  // b_in [H]
      (const float*)d_in[4],  // rms_w [NBLK,H]
      (const float*)d_in[5],  // W_ih [NBLK,4H,H]
      (const float*)d_in[6],  // W_hh [NBLK,4H,H]
      (const float*)d_in[7],  // b_ih [NBLK,4H]
      (const float*)d_in[8],  // b_hh [NBLK,4H]
      (const float*)d_in[9],  // head_w [NINS,H]
      (const float*)d_in[10], // head_b [NINS]
      (float*)d_out);
}